// Round 12
// baseline (126.650 us; speedup 1.0000x reference)
//
#include <hip/hip_runtime.h>
#include <math.h>

#define NPTS 512
#define NBATCH 64
#define NROWS (NPTS * NBATCH)   // 32768
#define LARGEV 1000000.0f
#define RPW 4                   // rows per wave in the MLP phases

typedef float v2f __attribute__((ext_vector_type(2)));
typedef short bf16x8 __attribute__((ext_vector_type(8)));   // 8 bf16 = 4 VGPRs
typedef float f32x4 __attribute__((ext_vector_type(4)));

__device__ __forceinline__ float rdlane(float v, int l) {
  return __uint_as_float((unsigned)__builtin_amdgcn_readlane((int)__float_as_uint(v), l));
}
__device__ __forceinline__ void pk_fma(v2f& acc, float s, v2f w) {
  acc = __builtin_elementwise_fma(w, (v2f){s, s}, acc);
}
// manual bf16 RTNE; inputs finite here
__device__ __forceinline__ unsigned short f2bf(float f) {
  unsigned u = __float_as_uint(f);
  u += 0x7FFFu + ((u >> 16) & 1u);
  return (unsigned short)(u >> 16);
}
__device__ __forceinline__ float bf2f(unsigned short h) {
  return __uint_as_float(((unsigned)h) << 16);
}

// ---------------------------------------------------------------------------
// W2 pre-split into MFMA B-fragment order (hi/lo bf16 planes in d_ws).
// Frag fi = (n_tile*4 + kk)*64 + lane: n = n_tile*16+(lane&15),
// k = kk*32 + (lane>>4)*8 + j.   (r11-verified)
// ---------------------------------------------------------------------------
__global__ __launch_bounds__(256) void w2prep(const float* __restrict__ W2,
                                              unsigned short* __restrict__ w2p) {
  const int t = blockIdx.x * 256 + threadIdx.x;   // 0..2047
  const int lane = t & 63;
  const int kk = (t >> 6) & 3;
  const int nt = t >> 8;                           // 0..7
  const int n  = nt * 16 + (lane & 15);
  const int k0 = kk * 32 + ((lane >> 4) << 3);
  unsigned hv[4], lv[4];
#pragma unroll
  for (int jp = 0; jp < 4; ++jp) {
    const float va = W2[(k0 + 2 * jp) * 128 + n];
    const float vb = W2[(k0 + 2 * jp + 1) * 128 + n];
    const unsigned short ha = f2bf(va), hb = f2bf(vb);
    const unsigned short la = f2bf(va - bf2f(ha)), lb = f2bf(vb - bf2f(hb));
    hv[jp] = (unsigned)ha | ((unsigned)hb << 16);
    lv[jp] = (unsigned)la | ((unsigned)lb << 16);
  }
  const int fi = (nt * 4 + kk) * 64 + lane;
  ((uint4*)w2p)[fi] = make_uint4(hv[0], hv[1], hv[2], hv[3]);
  ((uint4*)(w2p + 16384))[fi] = make_uint4(lv[0], lv[1], lv[2], lv[3]);
}

// ---------------------------------------------------------------------------
// Round-12 = r11 arithmetic re-tiled for latency hiding. Evidence (r11):
// per-SIMD VALU issue ~17% at 4 waves/SIMD -> stall-bound, need TLP.
//  - grid 2048 x (16 rows x 16 j-chunks): 32 pair-iters/lane, 8 blocks/CU
//    from grid.
//  - LDS diet 30.2->23.1KB -> 6 blocks/CU: sector counts packed 2/word
//    (u16 halves, atomicAdd 1 vs 0x10000; max 32/half; barrier before
//    readback since tid and tid^128 are in different waves).
// scru word map: [0,2304) sector min (9 planes x 256), [2304,3072) dir min
// (3 x 256), [3072,4224) packed counts (9 x 128). gT (8704B) aliases from 0.
// MFMA phase 3 (r11-verified layouts): 1 M-tile, wave owns N-tiles {2w,2w+1}.
// ---------------------------------------------------------------------------
__global__ __launch_bounds__(256, 4) void fused_kernel(const float* __restrict__ pos,
    const void* __restrict__ kpm,
    const float* __restrict__ W1, const float* __restrict__ b1,
    const float* __restrict__ gamma, const float* __restrict__ beta,
    const unsigned short* __restrict__ w2p, const float* __restrict__ b2,
    float* __restrict__ out) {
  __shared__ float2 sp[NPTS];                          //  4096 B
  __shared__ __align__(16) unsigned scru[4224];        // 16896 B (see map)
  __shared__ float xs[16 * 33];                        //  2112 B
  __shared__ int sflag, sMasked;
  const int b  = blockIdx.x >> 5;
  const int i0 = (blockIdx.x & 31) << 4;
  const int tid = threadIdx.x;

  // ---- inline mask-dtype sniff over first 2KB of the raw mask buffer ----
  if (tid == 0) { sflag = 0; sMasked = 0; }
  __syncthreads();
  {
    const unsigned int* rw = (const unsigned int*)kpm;
    const unsigned int w0 = rw[tid];
    const unsigned int w1 = rw[tid + 256];
    int f = 0;
    if (w0 == 0x3f800000u || w1 == 0x3f800000u) f |= 2;
    if (w0 > 1u || w1 > 1u) f |= 1;
    if (f) atomicOr(&sflag, f);
  }
  __syncthreads();
  const int fmt = sflag;   // 2=>f32, 1=>bytes, 0=>i32

  // ---- stage positions (NaN for masked), count masked via ballot ----
  for (int t = tid; t < NPTS; t += 256) {
    bool m;
    if (fmt & 2)      m = ((const float*)kpm)[b * NPTS + t] != 0.0f;
    else if (fmt & 1) m = ((const unsigned char*)kpm)[b * NPTS + t] != 0;
    else              m = ((const int*)kpm)[b * NPTS + t] != 0;
    float2 p = ((const float2*)pos)[b * NPTS + t];
    if (m) { p.x = __builtin_nanf(""); p.y = p.x; }
    sp[t] = p;
    unsigned long long bal = __ballot(m);
    if ((tid & 63) == 0) atomicAdd(&sMasked, __popcll(bal));
  }
#pragma unroll
  for (int k = 0; k < 9; ++k) scru[k * 256 + tid] = __float_as_uint(LARGEV);
#pragma unroll
  for (int k = 0; k < 3; ++k) scru[2304 + k * 256 + tid] = __float_as_uint(LARGEV);
  if (tid < 128) {
#pragma unroll
    for (int k = 0; k < 9; ++k) scru[3072 + k * 128 + tid] = 0u;
  }
  __syncthreads();
  const int M = sMasked;

  const int il = tid >> 4;       // row within block: 0..15
  const int jc = tid & 15;       // j-chunk: 0..15
  const int i  = i0 + il;
  const float2 pi = ((const float2*)pos)[b * NPTS + i];

  const float T5 = __uint_as_float(0x41C7FFFFu);   // 25 - 2^-19
  const unsigned cntAdd = (tid & 128) ? 0x10000u : 1u;
  const int cbase = 3072 + (tid & 127);
  unsigned cu = 0u, cd = 0u, asum = 0u;
  float sumd = 0.0f;

#pragma unroll 4
  for (int jj = 0; jj < 32; ++jj) {
    const int j = (jj << 4) + jc;
    const float2 pj = sp[j];
    const float dx = __fsub_rn(pj.x, pi.x);
    const float dy = __fsub_rn(pj.y, pi.y);
    float d2 = __fadd_rn(__fadd_rn(__fmul_rn(dx, dx), __fmul_rn(dy, dy)), 1e-8f);
    d2 = (j == i) ? __builtin_nanf("") : d2;

    const float hdy = __fmul_rn(fabsf(dy), 0.5f);
    const bool up = dx > hdy;
    const bool dn = dx < -hdy;

    const unsigned a = (d2 < 9.0f)  ? 0x01010101u
                     : ((d2 < T5)    ? 0x01010100u
                     : ((d2 < 64.0f) ? 0x01010000u
                     : ((d2 < 144.0f) ? 0x01000000u : 0u)));
    asum += a;
    cu += up ? a : 0u;
    cd += dn ? a : 0u;

    const float dist = __fsqrt_rn(d2);
    sumd += (dist < 1.0e30f) ? dist : 0.0f;

    const int dir = up ? 0 : (dn ? 1 : 2);
    atomicMin(&scru[2304 + dir * 256 + tid], __float_as_uint(dist));

    const int slot = (dy > 0.0f)
        ? ((dx > 0.0f) ? ((dy < dx) ? 4 : 5) : ((-dx < dy) ? 6 : 7))
        : ((dy < 0.0f) ? ((dx < 0.0f) ? ((dx < dy) ? 0 : 1) : ((dx < -dy) ? 2 : 3))
                       : ((dx > 0.0f) ? 4 : 8));
    atomicMin(&scru[slot * 256 + tid], __float_as_uint(dist));
    atomicAdd(&scru[cbase + slot * 128], cntAdd);
  }
  __syncthreads();   // packed count halves come from two different waves

  const unsigned clp = asum - cu - cd;
  const int cshift = (tid & 128) ? 16 : 0;

  float cnt[12];
  cnt[0] = (float)(cu & 0xffu);  cnt[3] = (float)((cu >> 8) & 0xffu);
  cnt[6] = (float)((cu >> 16) & 0xffu);  cnt[9]  = (float)(cu >> 24);
  cnt[1] = (float)(cd & 0xffu);  cnt[4] = (float)((cd >> 8) & 0xffu);
  cnt[7] = (float)((cd >> 16) & 0xffu);  cnt[10] = (float)(cd >> 24);
  cnt[2] = (float)(clp & 0xffu); cnt[5] = (float)((clp >> 8) & 0xffu);
  cnt[8] = (float)((clp >> 16) & 0xffu); cnt[11] = (float)(clp >> 24);
  float scnt[8], smin[8], dmin[3];
#pragma unroll
  for (int k = 0; k < 8; ++k) {
    smin[k] = __uint_as_float(scru[k * 256 + tid]);
    scnt[k] = (float)((scru[3072 + k * 128 + (tid & 127)] >> cshift) & 0xffffu);
  }
#pragma unroll
  for (int k = 0; k < 3; ++k)
    dmin[k] = __uint_as_float(scru[2304 + k * 256 + tid]);

  // ---- reduce 16 chunk partials (lanes differing in bits 0..3) ----
#pragma unroll
  for (int k = 0; k < 12; ++k) {
    cnt[k] += __shfl_xor(cnt[k], 1); cnt[k] += __shfl_xor(cnt[k], 2);
    cnt[k] += __shfl_xor(cnt[k], 4); cnt[k] += __shfl_xor(cnt[k], 8);
  }
#pragma unroll
  for (int k = 0; k < 8; ++k) {
    scnt[k] += __shfl_xor(scnt[k], 1); scnt[k] += __shfl_xor(scnt[k], 2);
    scnt[k] += __shfl_xor(scnt[k], 4); scnt[k] += __shfl_xor(scnt[k], 8);
  }
  sumd += __shfl_xor(sumd, 1); sumd += __shfl_xor(sumd, 2);
  sumd += __shfl_xor(sumd, 4); sumd += __shfl_xor(sumd, 8);
#pragma unroll
  for (int k = 0; k < 3; ++k) {
    dmin[k] = fminf(dmin[k], __shfl_xor(dmin[k], 1));
    dmin[k] = fminf(dmin[k], __shfl_xor(dmin[k], 2));
    dmin[k] = fminf(dmin[k], __shfl_xor(dmin[k], 4));
    dmin[k] = fminf(dmin[k], __shfl_xor(dmin[k], 8));
  }
#pragma unroll
  for (int k = 0; k < 8; ++k) {
    smin[k] = fminf(smin[k], __shfl_xor(smin[k], 1));
    smin[k] = fminf(smin[k], __shfl_xor(smin[k], 2));
    smin[k] = fminf(smin[k], __shfl_xor(smin[k], 4));
    smin[k] = fminf(smin[k], __shfl_xor(smin[k], 8));
  }

  // ---- park row il's 33 feats (writer lane il*16 is in consumer wave il/4) --
  if (jc == 0) {
    const bool own_unmasked = !isnan(sp[i].x);
    const float vcnt = fmaxf((float)(NPTS - M - (own_unmasked ? 1 : 0)), 1.0f);
    float* f = &xs[il * 33];
#pragma unroll
    for (int k = 0; k < 12; ++k) f[k] = cnt[k];
    f[12] = fminf(dmin[0] * 0.1f, 1.0f);
    f[13] = fminf(dmin[1] * 0.1f, 1.0f);
    f[14] = fminf(dmin[2] * 0.1f, 1.0f);
#pragma unroll
    for (int k = 0; k < 8; ++k) {
      f[15 + 2 * k] = scnt[k];
      f[16 + 2 * k] = fminf(smin[k] * 0.1f, 1.0f);
    }
    f[31] = cnt[9] + cnt[10] + cnt[11];
    f[32] = fminf(sumd / vcnt * 0.1f, 1.0f);
  }

  // ======================= MLP =======================
  const int w = tid >> 6;
  const int l = tid & 63;
  const float* __restrict__ xsf = xs + w * (RPW * 33);   // wave's 132 floats

  float xreg[3];
  xreg[0] = xsf[l];
  xreg[1] = xsf[64 + l];
  xreg[2] = (l < 4) ? xsf[128 + l] : 0.0f;

  const v2f b1v = ((const v2f*)b1)[l];
  const v2f gav = ((const v2f*)gamma)[l];
  const v2f bev = ((const v2f*)beta)[l];
  const v2f* __restrict__ W1v = (const v2f*)W1;

  // ---- phase 1: h = x @ W1 + b1 (readlane broadcast + packed fma) ----
  v2f h[RPW];
#pragma unroll
  for (int r = 0; r < RPW; ++r) h[r] = b1v;
#pragma unroll
  for (int k = 0; k < 33; ++k) {
    const v2f wv = W1v[k * 64 + l];
#pragma unroll
    for (int r = 0; r < RPW; ++r) {
      const int v = r * 33 + k;                 // compile-time, max 131
      pk_fma(h[r], rdlane(xreg[v >> 6], v & 63), wv);
    }
  }

  // ---- phase 2: LayerNorm + exact GELU ----
  float g0[RPW], g1[RPW];
#pragma unroll
  for (int r = 0; r < RPW; ++r) {
    float s = h[r].x + h[r].y;
#pragma unroll
    for (int o = 32; o > 0; o >>= 1) s += __shfl_xor(s, o);
    const float mu = s * 0.0078125f;
    const float d0 = h[r].x - mu, d1 = h[r].y - mu;
    float v = d0 * d0 + d1 * d1;
#pragma unroll
    for (int o = 32; o > 0; o >>= 1) v += __shfl_xor(v, o);
    const float inv = 1.0f / __fsqrt_rn(v * 0.0078125f + 1e-5f);
    float a = d0 * inv * gav.x + bev.x;
    float bb = d1 * inv * gav.y + bev.y;
    g0[r] = 0.5f * a * (1.0f + erff(a * 0.70710678118654752f));
    g1[r] = 0.5f * bb * (1.0f + erff(bb * 0.70710678118654752f));
  }

  // ---- alias barrier: scru reads done; gT overlays scru word 0 ----
  __syncthreads();
  unsigned short* gThi = (unsigned short*)scru;     // 16 rows x stride 136
  unsigned short* gTlo = gThi + 16 * 136;           // total 8704 B <= 16896 B
#pragma unroll
  for (int r = 0; r < RPW; ++r) {
    const unsigned short h0 = f2bf(g0[r]);
    const unsigned short h1 = f2bf(g1[r]);
    const unsigned short l0 = f2bf(g0[r] - bf2f(h0));
    const unsigned short l1 = f2bf(g1[r] - bf2f(h1));
    const int row = RPW * w + r;
    *(unsigned*)&gThi[row * 136 + 2 * l] = (unsigned)h0 | ((unsigned)h1 << 16);
    *(unsigned*)&gTlo[row * 136 + 2 * l] = (unsigned)l0 | ((unsigned)l1 << 16);
  }
  __syncthreads();   // cross-wave: every wave's A-frags span all 16 rows

  // ---- phase 3: out = g @ W2 + b2 via MFMA (split-bf16, 3 products) ----
  const int ntb = w * 2;           // wave's 2 N-tiles
  const int q = l >> 4, ln = l & 15;

  f32x4 acc[2];
#pragma unroll
  for (int t = 0; t < 2; ++t) {
    const float bv = b2[(ntb + t) * 16 + ln];
    acc[t] = (f32x4){bv, bv, bv, bv};
  }
  const bf16x8* __restrict__ Bhi = (const bf16x8*)w2p;
  const bf16x8* __restrict__ Blo = Bhi + 2048;
#pragma unroll
  for (int kk = 0; kk < 4; ++kk) {
    const bf16x8 Ah = *(const bf16x8*)&gThi[ln * 136 + kk * 32 + q * 8];
    const bf16x8 Al = *(const bf16x8*)&gTlo[ln * 136 + kk * 32 + q * 8];
#pragma unroll
    for (int t = 0; t < 2; ++t) {
      const int fi = ((ntb + t) * 4 + kk) * 64 + l;
      const bf16x8 Bh = Bhi[fi];
      const bf16x8 Bl = Blo[fi];
      acc[t] = __builtin_amdgcn_mfma_f32_16x16x32_bf16(Ah, Bh, acc[t], 0, 0, 0);
      acc[t] = __builtin_amdgcn_mfma_f32_16x16x32_bf16(Ah, Bl, acc[t], 0, 0, 0);
      acc[t] = __builtin_amdgcn_mfma_f32_16x16x32_bf16(Al, Bh, acc[t], 0, 0, 0);
    }
  }
  const int gr0 = blockIdx.x * 16 + q * 4;             // D row = quad*4 + reg
#pragma unroll
  for (int t = 0; t < 2; ++t) {
    const int col = (ntb + t) * 16 + ln;               // D col = lane&15
#pragma unroll
    for (int rg = 0; rg < 4; ++rg)
      out[(size_t)(gr0 + rg) * 128 + col] = acc[t][rg];
  }
}

extern "C" void kernel_launch(void* const* d_in, const int* in_sizes, int n_in,
                              void* d_out, int out_size, void* d_ws, size_t ws_size,
                              hipStream_t stream) {
  const float* positions = (const float*)d_in[0];
  const void*  kpm_raw   = d_in[1];
  const float* W1    = (const float*)d_in[2];
  const float* b1    = (const float*)d_in[3];
  const float* gamma = (const float*)d_in[4];
  const float* beta  = (const float*)d_in[5];
  const float* W2    = (const float*)d_in[6];
  const float* b2    = (const float*)d_in[7];
  float* out = (float*)d_out;
  unsigned short* w2p = (unsigned short*)d_ws;   // 64 KB: hi/lo bf16 B-frag planes

  w2prep<<<8, 256, 0, stream>>>(W2, w2p);
  fused_kernel<<<NBATCH * 32, 256, 0, stream>>>(positions, kpm_raw,
      W1, b1, gamma, beta, w2p, b2, out);
}